// Round 1
// baseline (273.712 us; speedup 1.0000x reference)
//
#include <hip/hip_runtime.h>

// Problem constants from the reference: B,C,H,W = 32,1,720,1280
constexpr int Bn = 32;
constexpr int Hn = 720;
constexpr int Wn = 1280;
constexpr int WIN = 512;   // per-wave staged window (floats per source row)

// Async global->LDS: 16B/lane x 64 lanes = 1024B per issue, no VGPR round-trip.
#define GLL(g, l) __builtin_amdgcn_global_load_lds(                         \
    (const __attribute__((address_space(1))) void*)(g),                     \
    (__attribute__((address_space(3))) void*)(l), 16, 0, 0)

// One block = one output row (b, y). 320 threads x 4 px = 1280 = W.
// Each WAVE stages its own 512-float window of the two source rows with
// global_load_lds into a wave-private LDS region -> NO __syncthreads at all,
// only an s_waitcnt vmcnt(0). Waves are fully decoupled (latency-bound fix).
__global__ __launch_bounds__(320) void warp_kernel(
    const float* __restrict__ img,
    const float* __restrict__ disp,
    float* __restrict__ out)
{
    // wave w owns srow[w*1024 .. w*1024+1023]:
    //   [0,512)    = window of row y0c
    //   [512,1024) = window of row y1c
    __shared__ float srow[5 * 2 * WIN];   // 20480 B

    const int blk  = blockIdx.x;          // b * Hn + y
    const int b    = blk / Hn;
    const int y    = blk - b * Hn;
    const int tid  = threadIdx.x;
    const int lane = tid & 63;
    const int wid  = tid >> 6;

    // ---- vertical coordinate (block-uniform) ----
    // Algebraically identical to the reference chain: iy = y*H/(H-1) - 0.5
    constexpr float sy = (float)Hn / (float)(Hn - 1);
    const float iy  = fmaf((float)y, sy, -0.5f);
    const float fy0 = floorf(iy);
    float wy1 = iy - fy0;
    float wy0 = 1.0f - wy1;
    const int y0 = (int)fy0;
    const int y1 = y0 + 1;
    // Fold y-validity into the (block-uniform) weights: zero contribution
    // instead of masking gathered values -> zero per-pixel cost.
    if (y0 < 0)   wy0 = 0.0f;
    if (y1 >= Hn) wy1 = 0.0f;
    const int y0c = min(max(y0, 0), Hn - 1);
    const int y1c = min(max(y1, 0), Hn - 1);

    const float* imb = img + (long long)b * (Hn * Wn);

    // ---- per-wave gather window ----
    // Wave covers pixels [xs, xs+256). With disp in [0,64) and scale
    // W/(W-1), every (clamped) gather index lies in [xs-66, xs+256]; a
    // 512-float window starting at clamp(xs-128, 0, W-512) covers it with
    // margin. ws is always a multiple of 16 floats -> 64B-aligned loads.
    const int xs = wid << 8;
    const int ws = min(max(xs - 128, 0), Wn - WIN);

    float* wv = srow + (wid << 10);
    const float* src0 = imb + y0c * Wn + ws;
    const float* src1 = imb + y1c * Wn + ws;

    GLL(src0 +       (lane << 2), wv +             (lane << 2));
    GLL(src0 + 256 + (lane << 2), wv + 256 +       (lane << 2));
    GLL(src1 +       (lane << 2), wv + WIN +       (lane << 2));
    GLL(src1 + 256 + (lane << 2), wv + WIN + 256 + (lane << 2));

    const int base = blk * Wn + (tid << 2);   // flat pixel index (fits int)
    const float4 d4 = *reinterpret_cast<const float4*>(disp + base);

    // Wave-private staging: drain the VM queue (global_load_lds counts in
    // vmcnt). No block barrier needed — no cross-wave LDS access.
    asm volatile("s_waitcnt vmcnt(0)" ::: "memory");

    // ---- horizontal sampling ----
    // ix = (xf - d) * W/(W-1) - 0.5  (exact algebraic collapse of the
    // reference normalization chain; sub + fma instead of 5 ops)
    constexpr float sx = (float)Wn / (float)(Wn - 1);
    const float xf0 = (float)(tid << 2);
    const float dv[4] = {d4.x, d4.y, d4.z, d4.w};
    float res[4];

#pragma unroll
    for (int i = 0; i < 4; ++i) {
        const float ix  = fmaf(xf0 + (float)i - dv[i], sx, -0.5f);
        const float fx0 = floorf(ix);
        float wx1 = ix - fx0;
        float wx0 = 1.0f - wx1;
        const int x0 = (int)fx0;
        const int x1 = x0 + 1;
        // validity folded into weights; single unsigned compare each
        wx0 = ((unsigned)x0 < (unsigned)Wn) ? wx0 : 0.0f;
        wx1 = ((unsigned)x1 < (unsigned)Wn) ? wx1 : 0.0f;
        const int xl0 = min(max(x0, 0), Wn - 1) - ws;   // in [0, 511]
        const int xl1 = min(max(x1, 0), Wn - 1) - ws;   // in [0, 511]

        const float v00 = wv[xl0];          // ds_read_b32, offset 0
        const float v01 = wv[xl1];
        const float v10 = wv[xl0 + WIN];    // same addr reg, offset:2048
        const float v11 = wv[xl1 + WIN];

        // 6-op blend: res = (v00*wy0 + v10*wy1)*wx0 + (v01*wy0 + v11*wy1)*wx1
        const float t0 = v00 * wy0 + v10 * wy1;
        const float t1 = v01 * wy0 + v11 * wy1;
        res[i] = t0 * wx0 + t1 * wx1;
    }

    *reinterpret_cast<float4*>(out + base) =
        make_float4(res[0], res[1], res[2], res[3]);
}

extern "C" void kernel_launch(void* const* d_in, const int* in_sizes, int n_in,
                              void* d_out, int out_size, void* d_ws, size_t ws_size,
                              hipStream_t stream) {
    const float* img  = (const float*)d_in[0];   // right_img [32,1,720,1280] fp32
    const float* disp = (const float*)d_in[1];   // disp      [32,1,720,1280] fp32
    float* out = (float*)d_out;                  // [32,1,720,1280] fp32

    const int grid  = Bn * Hn;   // 23040 blocks, one per output row
    const int block = 320;       // 5 waves; 4 px/thread covers W=1280

    warp_kernel<<<grid, block, 0, stream>>>(img, disp, out);
}